// Round 13
// baseline (428.443 us; speedup 1.0000x reference)
//
#include <hip/hip_runtime.h>

#define C0 10000
#define C1 30000
#define C2 50000

typedef __attribute__((ext_vector_type(8))) short short8;
typedef __attribute__((ext_vector_type(8))) unsigned short ushort8;
typedef __attribute__((ext_vector_type(4))) float f32x4;

__device__ __forceinline__ unsigned short f2bf(float f) {
    unsigned int u = __float_as_uint(f);
    u += 0x7FFF + ((u >> 16) & 1);   // round-to-nearest-even
    return (unsigned short)(u >> 16);
}

// ---------------- ws layout (bf16 elements) ----------------
#define SZ_IN    (4096 * 1024)
#define OFF_IN   0
#define HW_ROWSP 10240                 // >= 79*128 = 10112
#define SZ_HW    (HW_ROWSP * 1024)
#define REAL_HW  (10002 * 1024)
#define OFF_HW   (OFF_IN + SZ_IN)
// merged proj weights [512,1024]: rows 0-255 proj0_w, 256-319 proj1_w, 320-511 zero
#define OFF_PJ   (OFF_HW + SZ_HW)
#define SZ_PJ    (512 * 1024)
#define PJ_P0    (256 * 1024)
#define PJ_P1    (64 * 1024)
#define O_ROWSP  20096                 // 157 * 128 (128-wide tail tiles)
#define SZ_O0    (O_ROWSP * 256)
#define REAL_O0  (20000 * 256)
#define OFF_O0   (OFF_PJ + SZ_PJ)
#define SZ_O1    (O_ROWSP * 64)
#define REAL_O1  (20000 * 64)
#define OFF_O1   (OFF_O0 + SZ_O0)
#define CVT_TOTAL (OFF_O1 + SZ_O1)
#define OFF_PP0C CVT_TOTAL             // compact p0 bf16 [<=4096, 256]
#define SZ_PP0C  (4096 * 256)
#define OFF_PP1C (OFF_PP0C + SZ_PP0C)  // compact p1 bf16 [<=4096, 64]
#define SZ_PP1C  (4096 * 64)
#define OFF_IDX  (OFF_PP1C + SZ_PP1C)  // int idx0[4096], idx1[4096], cnts[2]

// f32 -> bf16 conversion of all operands into ws (zero padding), + routing outputs,
// + (block 0) band-row index compaction — the scan hides under the other blocks.
__global__ __launch_bounds__(256) void convert_kernel(
    const float* __restrict__ in,  const float* __restrict__ hw,
    const float* __restrict__ p0w, const float* __restrict__ o0w,
    const float* __restrict__ p1w, const float* __restrict__ o1w,
    unsigned short* __restrict__ ws,
    const int* __restrict__ target,
    float* __restrict__ o3, float* __restrict__ o4, float* __restrict__ o5,
    int* __restrict__ idx0, int* __restrict__ idx1, int* __restrict__ cnts)
{
    if (blockIdx.x == 0) {
        __shared__ int wsum0[4], wsum1[4];
        __shared__ int base0s, base1s;
        const int tt = threadIdx.x, lane = tt & 63, wv = tt >> 6;
        if (tt == 0) { base0s = 0; base1s = 0; }
        __syncthreads();
        for (int r = 0; r < 16; r++) {
            int i2 = r * 256 + tt;
            int tg = target[i2];
            bool p0 = (tg >= C0) && (tg < C1);
            bool p1 = (tg >= C1) && (tg < C2);
            unsigned long long b0 = __ballot(p0);
            unsigned long long b1 = __ballot(p1);
            int pre0 = __popcll(b0 & ((1ull << lane) - 1));
            int pre1 = __popcll(b1 & ((1ull << lane) - 1));
            if (lane == 0) { wsum0[wv] = __popcll(b0); wsum1[wv] = __popcll(b1); }
            __syncthreads();
            int woff0 = base0s, woff1 = base1s;
            for (int k = 0; k < wv; k++) { woff0 += wsum0[k]; woff1 += wsum1[k]; }
            if (p0) idx0[woff0 + pre0] = i2;
            if (p1) idx1[woff1 + pre1] = i2;
            __syncthreads();
            if (tt == 0)
                for (int k = 0; k < 4; k++) { base0s += wsum0[k]; base1s += wsum1[k]; }
            __syncthreads();
        }
        for (int j = base0s + tt; j < 4096; j += 256) idx0[j] = 0;
        for (int j = base1s + tt; j < 4096; j += 256) idx1[j] = 0;
        if (tt == 0) { cnts[0] = base0s; cnts[1] = base1s; }
    }

    long long tid = (long long)blockIdx.x * blockDim.x + threadIdx.x;
    if (tid < 4096) {
        int tg = target[tid];
        bool m0 = (tg >= C0) && (tg < C1);
        bool m1 = (tg >= C1) && (tg < C2);
        o3[tid] = (float)(m0 ? C0 : (m1 ? (C0 + 1) : tg));
        o4[tid] = (float)(m0 ? (tg - C0) : 0);
        o5[tid] = (float)(m1 ? (tg - C1) : 0);
    }
    long long i = tid * 8;
    if (i >= CVT_TOTAL) return;
    const float* src;
    long long rel, real;
    if (i < OFF_HW)                      { src = in;  rel = i - OFF_IN;            real = SZ_IN;   }
    else if (i < OFF_PJ)                 { src = hw;  rel = i - OFF_HW;            real = REAL_HW; }
    else if (i < OFF_PJ + PJ_P0)         { src = p0w; rel = i - OFF_PJ;            real = PJ_P0;   }
    else if (i < OFF_PJ + PJ_P0 + PJ_P1) { src = p1w; rel = i - (OFF_PJ + PJ_P0);  real = PJ_P1;   }
    else if (i < OFF_O0)                 { src = p1w; rel = 1;                     real = 0;       }
    else if (i < OFF_O1)                 { src = o0w; rel = i - OFF_O0;            real = REAL_O0; }
    else                                 { src = o1w; rel = i - OFF_O1;            real = REAL_O1; }
    ushort8 o;
    if (rel < real) {
        float4 v0 = *(const float4*)(src + rel);
        float4 v1 = *(const float4*)(src + rel + 4);
        o[0] = f2bf(v0.x); o[1] = f2bf(v0.y); o[2] = f2bf(v0.z); o[3] = f2bf(v0.w);
        o[4] = f2bf(v1.x); o[5] = f2bf(v1.y); o[6] = f2bf(v1.z); o[7] = f2bf(v1.w);
    } else {
        o = (ushort8)0;
    }
    *(ushort8*)(ws + i) = o;
}

// ================= proj: gathered-A GEMM, both bands in one dispatch =================
#define BM 128
#define BN 128
#define BK 64

__global__ __launch_bounds__(256) void proj_gather(
    const unsigned short* __restrict__ A,    // in_bf [4096,1024]
    const unsigned short* __restrict__ pjw,  // [512,1024] padded
    unsigned short* __restrict__ pp0c, unsigned short* __restrict__ pp1c,
    const int* __restrict__ idx0, const int* __restrict__ idx1,
    const int* __restrict__ cnts)
{
    const int band = blockIdx.z;
    if (band == 1 && blockIdx.x > 0) return;
    const int* idx = band ? idx1 : idx0;
    const int cnt = cnts[band];
    const int mBase = blockIdx.y * BM;
    if (mBase >= cnt) return;
    const unsigned short* B = pjw + (band ? (size_t)PJ_P0 : 0);
    const int Nn = band ? 64 : 256;
    unsigned short* Cb = band ? pp1c : pp0c;
    const int K = 1024;

    __shared__ unsigned short As[BM * BK];
    __shared__ unsigned short Bs[BN * BK];

    const int t    = threadIdx.x;
    const int lane = t & 63;
    const int w    = t >> 6;
    const int wr   = w >> 1;
    const int wc   = w & 1;
    const int nBase = blockIdx.x * BN;
    const int srow = lane >> 3;
    const int scol = (lane & 7) * 8;

    int rowsIdx[4];
    #pragma unroll
    for (int c = 0; c < 4; c++)
        rowsIdx[c] = idx[mBase + w * 32 + c * 8 + srow];

    f32x4 acc[4][4] = {};

    for (int k0 = 0; k0 < K; k0 += BK) {
        #pragma unroll
        for (int c = 0; c < 4; c++) {
            const int rbase = w * 32 + c * 8;
            const unsigned short* ga = A + (size_t)rowsIdx[c] * K + k0 + scol;
            __builtin_amdgcn_global_load_lds(
                (const __attribute__((address_space(1))) void*)ga,
                (__attribute__((address_space(3))) void*)&As[rbase * BK], 16, 0, 0);
            const unsigned short* gb = B + (size_t)(nBase + rbase + srow) * K + k0 + scol;
            __builtin_amdgcn_global_load_lds(
                (const __attribute__((address_space(1))) void*)gb,
                (__attribute__((address_space(3))) void*)&Bs[rbase * BK], 16, 0, 0);
        }
        __syncthreads();

        #pragma unroll
        for (int kk = 0; kk < BK / 32; kk++) {
            const int kOff = kk * 32 + (lane >> 4) * 8;
            short8 a4[4], b4[4];
            #pragma unroll
            for (int m = 0; m < 4; m++)
                a4[m] = *(const short8*)(&As[(wr * 64 + m * 16 + (lane & 15)) * BK + kOff]);
            #pragma unroll
            for (int n = 0; n < 4; n++)
                b4[n] = *(const short8*)(&Bs[(wc * 64 + n * 16 + (lane & 15)) * BK + kOff]);
            #pragma unroll
            for (int m = 0; m < 4; m++)
                #pragma unroll
                for (int n = 0; n < 4; n++)
                    acc[m][n] = __builtin_amdgcn_mfma_f32_16x16x32_bf16(
                        a4[m], b4[n], acc[m][n], 0, 0, 0);
        }
        __syncthreads();
    }

    #pragma unroll
    for (int m = 0; m < 4; m++)
        #pragma unroll
        for (int i = 0; i < 4; i++) {
            int grow = mBase + wr * 64 + m * 16 + (lane >> 4) * 4 + i;
            #pragma unroll
            for (int n = 0; n < 4; n++) {
                int gcol = nBase + wc * 64 + n * 16 + (lane & 15);
                if (gcol < Nn)
                    Cb[(size_t)grow * Nn + gcol] = f2bf(acc[m][n][i]);
            }
        }
}

// ===== MEGA: head + tails + fill, ALL uniform 128^2 m97-structure blocks =====
// 256 thr / 32 KB LDS -> ~3 blocks/CU co-residency: MFMA blocks and fill-write
// blocks share CUs chip-wide (the R8-verified pattern, now including the head).
// gemm slots: 0..2527 head | 2528..7551 tail0 | 7552..12575 tail1.
// grid = 4192 groups * 5 = 20960: per group 3 gemm slots + 2 fill slots.

#define HEAD_TILES 2528     // 79 bx * 32 by
#define TAIL_SL    5024     // 157 nb * 32 my
#define NGROUPS    4192
#define MEGA_GRID  (NGROUPS * 5)

__global__ __launch_bounds__(256) void mega128(
    const unsigned short* __restrict__ in_bf, const unsigned short* __restrict__ hw_bf,
    const unsigned short* __restrict__ pp0c,  const unsigned short* __restrict__ pp1c,
    const unsigned short* __restrict__ o0w,   const unsigned short* __restrict__ o1w,
    float* __restrict__ head_out, float* __restrict__ tail0, float* __restrict__ tail1,
    const int* __restrict__ idx0, const int* __restrict__ idx1,
    const int* __restrict__ cnts, const int* __restrict__ target)
{
    __shared__ unsigned short As[BM * BK];
    __shared__ unsigned short Bs[BN * BK];

    const int L = blockIdx.x;
    const int G = L / 5;
    const int r = L % 5;
    const int t = threadIdx.x;

    if (r >= 3) {
        // ---------- full-row zero-fill block ----------
        int f = G * 2 + (r - 3);
        if (f >= 8192) return;
        int row   = f >> 1;
        int which = f & 1;
        int tg = target[row];
        bool in = which ? (tg >= C1 && tg < C2) : (tg >= C0 && tg < C1);
        if (in) return;
        float4* dst = (float4*)((which ? tail1 : tail0) + (size_t)row * 20000);
        float4 z = {0.f, 0.f, 0.f, 0.f};
        for (int q = t; q < 5000; q += 256) dst[q] = z;
        return;
    }

    // ---------- GEMM slot ----------
    const int s = G * 3 + r;            // 0..12575
    const unsigned short *A, *B;
    float* Cp;
    const int* idx = nullptr;
    int K, Nn, Mlimit, mBase, nBase;

    if (s < HEAD_TILES) {
        int by = s % 32, bx = s / 32;   // B-panel-major: 32 consecutive blocks share bx
        A = in_bf; B = hw_bf; Cp = head_out;
        K = 1024; Nn = 10002; Mlimit = 4096;
        mBase = by * 128; nBase = bx * 128;
    } else if (s < HEAD_TILES + TAIL_SL) {
        int u = s - HEAD_TILES;
        int my = u % 32, nb = u / 32;
        A = pp0c; B = o0w; Cp = tail0; idx = idx0;
        K = 256; Nn = 20000; Mlimit = cnts[0];
        mBase = my * 128; nBase = nb * 128;
    } else {
        int u = s - HEAD_TILES - TAIL_SL;
        int my = u % 32, nb = u / 32;
        A = pp1c; B = o1w; Cp = tail1; idx = idx1;
        K = 64; Nn = 20000; Mlimit = cnts[1];
        mBase = my * 128; nBase = nb * 128;
    }
    if (mBase >= Mlimit) return;

    const int lane = t & 63;
    const int w    = t >> 6;
    const int wr   = w >> 1;
    const int wc   = w & 1;
    const int srow = lane >> 3;
    const int scol = (lane & 7) * 8;

    f32x4 acc[4][4] = {};

    for (int k0 = 0; k0 < K; k0 += BK) {
        #pragma unroll
        for (int c = 0; c < 4; c++) {
            const int rbase = w * 32 + c * 8;
            const unsigned short* ga = A + (size_t)(mBase + rbase + srow) * K + k0 + scol;
            __builtin_amdgcn_global_load_lds(
                (const __attribute__((address_space(1))) void*)ga,
                (__attribute__((address_space(3))) void*)&As[rbase * BK], 16, 0, 0);
            const unsigned short* gb = B + (size_t)(nBase + rbase + srow) * K + k0 + scol;
            __builtin_amdgcn_global_load_lds(
                (const __attribute__((address_space(1))) void*)gb,
                (__attribute__((address_space(3))) void*)&Bs[rbase * BK], 16, 0, 0);
        }
        __syncthreads();

        #pragma unroll
        for (int kk = 0; kk < BK / 32; kk++) {
            const int kOff = kk * 32 + (lane >> 4) * 8;
            short8 a4[4], b4[4];
            #pragma unroll
            for (int m = 0; m < 4; m++)
                a4[m] = *(const short8*)(&As[(wr * 64 + m * 16 + (lane & 15)) * BK + kOff]);
            #pragma unroll
            for (int n = 0; n < 4; n++)
                b4[n] = *(const short8*)(&Bs[(wc * 64 + n * 16 + (lane & 15)) * BK + kOff]);
            #pragma unroll
            for (int m = 0; m < 4; m++)
                #pragma unroll
                for (int n = 0; n < 4; n++)
                    acc[m][n] = __builtin_amdgcn_mfma_f32_16x16x32_bf16(
                        a4[m], b4[n], acc[m][n], 0, 0, 0);
        }
        __syncthreads();
    }

    #pragma unroll
    for (int m = 0; m < 4; m++)
        #pragma unroll
        for (int i = 0; i < 4; i++) {
            int grow = mBase + wr * 64 + m * 16 + (lane >> 4) * 4 + i;
            if (grow < Mlimit) {
                int gr = idx ? idx[grow] : grow;
                #pragma unroll
                for (int n = 0; n < 4; n++) {
                    int gcol = nBase + wc * 64 + n * 16 + (lane & 15);
                    if (gcol < Nn)
                        Cp[(size_t)gr * Nn + gcol] = acc[m][n][i];
                }
            }
        }
}

extern "C" void kernel_launch(void* const* d_in, const int* in_sizes, int n_in,
                              void* d_out, int out_size, void* d_ws, size_t ws_size,
                              hipStream_t stream)
{
    const float* input   = (const float*)d_in[0];
    const int*   target  = (const int*)  d_in[1];
    const float* head_w  = (const float*)d_in[2];
    const float* proj0_w = (const float*)d_in[3];
    const float* out0_w  = (const float*)d_in[4];
    const float* proj1_w = (const float*)d_in[5];
    const float* out1_w  = (const float*)d_in[6];

    const int N = 4096;

    float* out      = (float*)d_out;
    float* head_out = out;
    float* tail0    = head_out + (size_t)N * 10002;
    float* tail1    = tail0 + (size_t)N * 20000;
    float* o3       = tail1 + (size_t)N * 20000;
    float* o4       = o3 + N;
    float* o5       = o4 + N;

    unsigned short* ws = (unsigned short*)d_ws;
    unsigned short* in_bf  = ws + OFF_IN;
    unsigned short* hw_bf  = ws + OFF_HW;
    unsigned short* pjw_bf = ws + OFF_PJ;
    unsigned short* o0w_bf = ws + OFF_O0;
    unsigned short* o1w_bf = ws + OFF_O1;
    unsigned short* pp0c   = ws + OFF_PP0C;
    unsigned short* pp1c   = ws + OFF_PP1C;
    int* idx0 = (int*)(ws + OFF_IDX);
    int* idx1 = idx0 + 4096;
    int* cnts = idx1 + 4096;

    // 1. convert all operands to bf16 + routing outputs + (block 0) idx compaction
    convert_kernel<<<dim3((CVT_TOTAL / 8 + 255) / 256), dim3(256), 0, stream>>>(
        input, head_w, proj0_w, out0_w, proj1_w, out1_w, ws, target, o3, o4, o5,
        idx0, idx1, cnts);

    // 2. compacted projections, both bands (gathered A rows)
    proj_gather<<<dim3(2, N / BM, 2), dim3(256), 0, stream>>>(
        in_bf, pjw_bf, pp0c, pp1c, idx0, idx1, cnts);

    // 3. MEGA: head + tails + fill, uniform 128^2 m97 blocks (~3 blocks/CU)
    mega128<<<dim3(MEGA_GRID), dim3(256), 0, stream>>>(
        in_bf, hw_bf, pp0c, pp1c, o0w_bf, o1w_bf,
        head_out, tail0, tail1, idx0, idx1, cnts, target);
}

// Round 14
// 311.238 us; speedup vs baseline: 1.3766x; 1.3766x over previous
//
#include <hip/hip_runtime.h>

#define C0 10000
#define C1 30000
#define C2 50000

typedef __attribute__((ext_vector_type(8))) short short8;
typedef __attribute__((ext_vector_type(8))) unsigned short ushort8;
typedef __attribute__((ext_vector_type(4))) float f32x4;

__device__ __forceinline__ unsigned short f2bf(float f) {
    unsigned int u = __float_as_uint(f);
    u += 0x7FFF + ((u >> 16) & 1);   // round-to-nearest-even
    return (unsigned short)(u >> 16);
}

// ---------------- ws layout (bf16 elements) ----------------
#define SZ_IN    (4096 * 1024)
#define OFF_IN   0
#define HW_ROWSP 10240                 // 40 * 256
#define SZ_HW    (HW_ROWSP * 1024)
#define REAL_HW  (10002 * 1024)
#define OFF_HW   (OFF_IN + SZ_IN)
// merged proj weights [512,1024]: rows 0-255 proj0_w, 256-319 proj1_w, 320-511 zero
#define OFF_PJ   (OFF_HW + SZ_HW)
#define SZ_PJ    (512 * 1024)
#define PJ_P0    (256 * 1024)
#define PJ_P1    (64 * 1024)
#define O_ROWSP  20224                 // 79 * 256 (256-wide tail tiles)
#define SZ_O0    (O_ROWSP * 256)
#define REAL_O0  (20000 * 256)
#define OFF_O0   (OFF_PJ + SZ_PJ)
#define SZ_O1    (O_ROWSP * 64)
#define REAL_O1  (20000 * 64)
#define OFF_O1   (OFF_O0 + SZ_O0)
#define CVT_TOTAL (OFF_O1 + SZ_O1)
#define OFF_PP0C CVT_TOTAL             // compact p0 bf16 [<=4096, 256]
#define SZ_PP0C  (4096 * 256)
#define OFF_PP1C (OFF_PP0C + SZ_PP0C)  // compact p1 bf16 [<=4096, 64]
#define SZ_PP1C  (4096 * 64)
#define OFF_IDX  (OFF_PP1C + SZ_PP1C)  // int idx0[4096], idx1[4096], cnts[2]

// f32 -> bf16 conversion of all operands into ws (zero padding), + routing outputs,
// + (block 0) band-row index compaction — the scan hides under the other blocks.
__global__ __launch_bounds__(256) void convert_kernel(
    const float* __restrict__ in,  const float* __restrict__ hw,
    const float* __restrict__ p0w, const float* __restrict__ o0w,
    const float* __restrict__ p1w, const float* __restrict__ o1w,
    unsigned short* __restrict__ ws,
    const int* __restrict__ target,
    float* __restrict__ o3, float* __restrict__ o4, float* __restrict__ o5,
    int* __restrict__ idx0, int* __restrict__ idx1, int* __restrict__ cnts)
{
    if (blockIdx.x == 0) {
        __shared__ int wsum0[4], wsum1[4];
        __shared__ int base0s, base1s;
        const int tt = threadIdx.x, lane = tt & 63, wv = tt >> 6;
        if (tt == 0) { base0s = 0; base1s = 0; }
        __syncthreads();
        for (int r = 0; r < 16; r++) {
            int i2 = r * 256 + tt;
            int tg = target[i2];
            bool p0 = (tg >= C0) && (tg < C1);
            bool p1 = (tg >= C1) && (tg < C2);
            unsigned long long b0 = __ballot(p0);
            unsigned long long b1 = __ballot(p1);
            int pre0 = __popcll(b0 & ((1ull << lane) - 1));
            int pre1 = __popcll(b1 & ((1ull << lane) - 1));
            if (lane == 0) { wsum0[wv] = __popcll(b0); wsum1[wv] = __popcll(b1); }
            __syncthreads();
            int woff0 = base0s, woff1 = base1s;
            for (int k = 0; k < wv; k++) { woff0 += wsum0[k]; woff1 += wsum1[k]; }
            if (p0) idx0[woff0 + pre0] = i2;
            if (p1) idx1[woff1 + pre1] = i2;
            __syncthreads();
            if (tt == 0)
                for (int k = 0; k < 4; k++) { base0s += wsum0[k]; base1s += wsum1[k]; }
            __syncthreads();
        }
        for (int j = base0s + tt; j < 4096; j += 256) idx0[j] = 0;
        for (int j = base1s + tt; j < 4096; j += 256) idx1[j] = 0;
        if (tt == 0) { cnts[0] = base0s; cnts[1] = base1s; }
    }

    long long tid = (long long)blockIdx.x * blockDim.x + threadIdx.x;
    if (tid < 4096) {
        int tg = target[tid];
        bool m0 = (tg >= C0) && (tg < C1);
        bool m1 = (tg >= C1) && (tg < C2);
        o3[tid] = (float)(m0 ? C0 : (m1 ? (C0 + 1) : tg));
        o4[tid] = (float)(m0 ? (tg - C0) : 0);
        o5[tid] = (float)(m1 ? (tg - C1) : 0);
    }
    long long i = tid * 8;
    if (i >= CVT_TOTAL) return;
    const float* src;
    long long rel, real;
    if (i < OFF_HW)                      { src = in;  rel = i - OFF_IN;            real = SZ_IN;   }
    else if (i < OFF_PJ)                 { src = hw;  rel = i - OFF_HW;            real = REAL_HW; }
    else if (i < OFF_PJ + PJ_P0)         { src = p0w; rel = i - OFF_PJ;            real = PJ_P0;   }
    else if (i < OFF_PJ + PJ_P0 + PJ_P1) { src = p1w; rel = i - (OFF_PJ + PJ_P0);  real = PJ_P1;   }
    else if (i < OFF_O0)                 { src = p1w; rel = 1;                     real = 0;       }
    else if (i < OFF_O1)                 { src = o0w; rel = i - OFF_O0;            real = REAL_O0; }
    else                                 { src = o1w; rel = i - OFF_O1;            real = REAL_O1; }
    ushort8 o;
    if (rel < real) {
        float4 v0 = *(const float4*)(src + rel);
        float4 v1 = *(const float4*)(src + rel + 4);
        o[0] = f2bf(v0.x); o[1] = f2bf(v0.y); o[2] = f2bf(v0.z); o[3] = f2bf(v0.w);
        o[4] = f2bf(v1.x); o[5] = f2bf(v1.y); o[6] = f2bf(v1.z); o[7] = f2bf(v1.w);
    } else {
        o = (ushort8)0;
    }
    *(ushort8*)(ws + i) = o;
}

// ================= proj: gathered-A GEMM, both bands in one dispatch =================
#define BM 128
#define BN 128
#define BK 64

__global__ __launch_bounds__(256) void proj_gather(
    const unsigned short* __restrict__ A,    // in_bf [4096,1024]
    const unsigned short* __restrict__ pjw,  // [512,1024] padded
    unsigned short* __restrict__ pp0c, unsigned short* __restrict__ pp1c,
    const int* __restrict__ idx0, const int* __restrict__ idx1,
    const int* __restrict__ cnts)
{
    const int band = blockIdx.z;
    if (band == 1 && blockIdx.x > 0) return;
    const int* idx = band ? idx1 : idx0;
    const int cnt = cnts[band];
    const int mBase = blockIdx.y * BM;
    if (mBase >= cnt) return;
    const unsigned short* B = pjw + (band ? (size_t)PJ_P0 : 0);
    const int Nn = band ? 64 : 256;
    unsigned short* Cb = band ? pp1c : pp0c;
    const int K = 1024;

    __shared__ unsigned short As[BM * BK];
    __shared__ unsigned short Bs[BN * BK];

    const int t    = threadIdx.x;
    const int lane = t & 63;
    const int w    = t >> 6;
    const int wr   = w >> 1;
    const int wc   = w & 1;
    const int nBase = blockIdx.x * BN;
    const int srow = lane >> 3;
    const int scol = (lane & 7) * 8;

    int rowsIdx[4];
    #pragma unroll
    for (int c = 0; c < 4; c++)
        rowsIdx[c] = idx[mBase + w * 32 + c * 8 + srow];

    f32x4 acc[4][4] = {};

    for (int k0 = 0; k0 < K; k0 += BK) {
        #pragma unroll
        for (int c = 0; c < 4; c++) {
            const int rbase = w * 32 + c * 8;
            const unsigned short* ga = A + (size_t)rowsIdx[c] * K + k0 + scol;
            __builtin_amdgcn_global_load_lds(
                (const __attribute__((address_space(1))) void*)ga,
                (__attribute__((address_space(3))) void*)&As[rbase * BK], 16, 0, 0);
            const unsigned short* gb = B + (size_t)(nBase + rbase + srow) * K + k0 + scol;
            __builtin_amdgcn_global_load_lds(
                (const __attribute__((address_space(1))) void*)gb,
                (__attribute__((address_space(3))) void*)&Bs[rbase * BK], 16, 0, 0);
        }
        __syncthreads();

        #pragma unroll
        for (int kk = 0; kk < BK / 32; kk++) {
            const int kOff = kk * 32 + (lane >> 4) * 8;
            short8 a4[4], b4[4];
            #pragma unroll
            for (int m = 0; m < 4; m++)
                a4[m] = *(const short8*)(&As[(wr * 64 + m * 16 + (lane & 15)) * BK + kOff]);
            #pragma unroll
            for (int n = 0; n < 4; n++)
                b4[n] = *(const short8*)(&Bs[(wc * 64 + n * 16 + (lane & 15)) * BK + kOff]);
            #pragma unroll
            for (int m = 0; m < 4; m++)
                #pragma unroll
                for (int n = 0; n < 4; n++)
                    acc[m][n] = __builtin_amdgcn_mfma_f32_16x16x32_bf16(
                        a4[m], b4[n], acc[m][n], 0, 0, 0);
        }
        __syncthreads();
    }

    #pragma unroll
    for (int m = 0; m < 4; m++)
        #pragma unroll
        for (int i = 0; i < 4; i++) {
            int grow = mBase + wr * 64 + m * 16 + (lane >> 4) * 4 + i;
            #pragma unroll
            for (int n = 0; n < 4; n++) {
                int gcol = nBase + wc * 64 + n * 16 + (lane & 15);
                if (gcol < Nn)
                    Cb[(size_t)grow * Nn + gcol] = f2bf(acc[m][n][i]);
            }
        }
}

// ===== FUSED: head + tails (256^2 4-phase GEMM) + non-band row fill, ONE dispatch =====
// Best-measured core (R9/R11): per phase {vmcnt(4); barrier; ds-reads; stage one
// quarter of next K-tile; setprio(1); 16 MFMA; setprio(0)}.
// R14 tweaks: fill quota only on NON-head blocks; head XCD swizzle uses the
// true XCD identity (5h mod 8) so same-XCD head blocks share B panels.

__device__ __forceinline__ short8 ldsw(const unsigned short* base, int row, int chunk) {
    int slot = chunk ^ (row & 7);
    return *(const short8*)(base + row * 64 + slot * 8);
}

#define STG(dstElemOff, srcPtr)                                                \
  __builtin_amdgcn_global_load_lds(                                            \
      (const __attribute__((address_space(1))) void*)(srcPtr),                 \
      (__attribute__((address_space(3))) void*)(lds + (dstElemOff)), 16, 0, 0);

#define STAGE_A(bf, h, kofs) {                                                 \
    STG((bf)*32768 + (h)*8192 + (w * 8) * 64,        pA[h] + (kofs));          \
    STG((bf)*32768 + (h)*8192 + (64 + w * 8) * 64,   pA[h] + (size_t)64 * K + (kofs)); }
#define STAGE_B(bf, h, kofs) {                                                 \
    STG((bf)*32768 + 16384 + (h)*8192 + (w * 8) * 64,      pB[h] + (kofs));    \
    STG((bf)*32768 + 16384 + (h)*8192 + (64 + w * 8) * 64, pB[h] + (size_t)64 * K + (kofs)); }

#define VM4()  asm volatile("s_waitcnt vmcnt(4)" ::: "memory")
#define BARF() { __builtin_amdgcn_s_barrier(); asm volatile("" ::: "memory"); }

#define NB_FUSED 3200
#define NB_NONHEAD 2560
#define TAIL_SLOTS 2528     // 2 bands * 79 nb * 16 my

__global__ __launch_bounds__(512) void fused_kernel(
    const unsigned short* __restrict__ in_bf, const unsigned short* __restrict__ hw_bf,
    const unsigned short* __restrict__ pp0c,  const unsigned short* __restrict__ pp1c,
    const unsigned short* __restrict__ o0w,   const unsigned short* __restrict__ o1w,
    float* __restrict__ head_out, float* __restrict__ tail0, float* __restrict__ tail1,
    const int* __restrict__ idx0, const int* __restrict__ idx1,
    const int* __restrict__ cnts, const int* __restrict__ target)
{
    __shared__ unsigned short lds[65536];   // 128 KB

    const int L    = blockIdx.x;
    const int t    = threadIdx.x;
    const int lane = t & 63;
    const int w    = t >> 6;
    const int wm   = w >> 2;
    const int wn   = w & 3;
    const int lr   = lane & 15;
    const int lq   = lane >> 4;
    const int lr3  = lane >> 3;
    const int swzc = ((lane & 7) ^ lr3) * 8;

    // ---- role decode ----
    const unsigned short *A = nullptr, *B = nullptr;
    float* Cp = nullptr;
    const int* idx = nullptr;
    int K = 0, NT = 0, Nn = 0, Mlimit = 0, mBase = 0, nBase = 0;
    int s = -1;
    bool live = false;
    const bool isHead = (L % 5 == 0);

    if (isHead) {
        int h = L / 5;                      // 0..639
        int x = (5 * h) & 7;                // true XCD of block L = 5h
        int swz = x * 80 + (h >> 3);        // bijective (gcd(5,8)=1)
        nBase = (swz >> 4) * 256;
        mBase = (swz & 15) * 256;
        A = in_bf; B = hw_bf; Cp = head_out;
        K = 1024; NT = 16; Nn = 10002; Mlimit = 4096;
        live = true;
    } else {
        s = L - L / 5 - 1;                  // 0..2559 dense over non-head blocks
        if (s < TAIL_SLOTS) {
            int band = s / 1264;
            int r    = s % 1264;
            nBase = (r / 16) * 256;
            mBase = (r % 16) * 256;
            if (band == 0) { A = pp0c; B = o0w; Cp = tail0; idx = idx0; K = 256; NT = 4; }
            else           { A = pp1c; B = o1w; Cp = tail1; idx = idx1; K = 64;  NT = 1; }
            Nn = 20000;
            Mlimit = cnts[band];
            live = (mBase < Mlimit);
        }
    }

    if (live) {
        const unsigned short* pA[2];
        const unsigned short* pB[2];
        #pragma unroll
        for (int h = 0; h < 2; h++) {
            pA[h] = A + (size_t)(mBase + h * 128 + w * 8 + lr3) * K + swzc;
            pB[h] = B + (size_t)(nBase + h * 128 + w * 8 + lr3) * K + swzc;
        }

        f32x4 acc[8][4] = {};
        short8 af[4][2], bf0[2][2], bf1[2][2];

        STAGE_A(0, 0, 0); STAGE_B(0, 0, 0); STAGE_B(0, 1, 0); STAGE_A(0, 1, 0);

        for (int kt = 0; kt < NT; ++kt) {
            const int cbuf = kt & 1, nb2 = cbuf ^ 1;
            const int kofs = (kt + 1) * 64;
            const unsigned short* Ab0 = lds + cbuf * 32768;
            const unsigned short* Ab1 = Ab0 + 8192;
            const unsigned short* Bb0 = Ab0 + 16384;
            const unsigned short* Bb1 = Ab0 + 24576;

            VM4(); BARF();
            #pragma unroll
            for (int m = 0; m < 4; m++)
                #pragma unroll
                for (int ks = 0; ks < 2; ks++)
                    af[m][ks] = ldsw(Ab0, wm * 64 + m * 16 + lr, ks * 4 + lq);
            #pragma unroll
            for (int n = 0; n < 2; n++)
                #pragma unroll
                for (int ks = 0; ks < 2; ks++)
                    bf0[n][ks] = ldsw(Bb0, wn * 32 + n * 16 + lr, ks * 4 + lq);
            STAGE_A(nb2, 0, kofs);
            __builtin_amdgcn_s_setprio(1);
            #pragma unroll
            for (int m = 0; m < 4; m++)
                #pragma unroll
                for (int n = 0; n < 2; n++)
                    #pragma unroll
                    for (int ks = 0; ks < 2; ks++)
                        acc[m][n] = __builtin_amdgcn_mfma_f32_16x16x32_bf16(
                            af[m][ks], bf0[n][ks], acc[m][n], 0, 0, 0);
            __builtin_amdgcn_s_setprio(0);

            VM4(); BARF();
            #pragma unroll
            for (int n = 0; n < 2; n++)
                #pragma unroll
                for (int ks = 0; ks < 2; ks++)
                    bf1[n][ks] = ldsw(Bb1, wn * 32 + n * 16 + lr, ks * 4 + lq);
            STAGE_B(nb2, 0, kofs);
            __builtin_amdgcn_s_setprio(1);
            #pragma unroll
            for (int m = 0; m < 4; m++)
                #pragma unroll
                for (int n = 0; n < 2; n++)
                    #pragma unroll
                    for (int ks = 0; ks < 2; ks++)
                        acc[m][2 + n] = __builtin_amdgcn_mfma_f32_16x16x32_bf16(
                            af[m][ks], bf1[n][ks], acc[m][2 + n], 0, 0, 0);
            __builtin_amdgcn_s_setprio(0);

            VM4(); BARF();
            #pragma unroll
            for (int m = 0; m < 4; m++)
                #pragma unroll
                for (int ks = 0; ks < 2; ks++)
                    af[m][ks] = ldsw(Ab1, wm * 64 + m * 16 + lr, ks * 4 + lq);
            STAGE_B(nb2, 1, kofs);
            __builtin_amdgcn_s_setprio(1);
            #pragma unroll
            for (int m = 0; m < 4; m++)
                #pragma unroll
                for (int n = 0; n < 2; n++)
                    #pragma unroll
                    for (int ks = 0; ks < 2; ks++)
                        acc[4 + m][2 + n] = __builtin_amdgcn_mfma_f32_16x16x32_bf16(
                            af[m][ks], bf1[n][ks], acc[4 + m][2 + n], 0, 0, 0);
            __builtin_amdgcn_s_setprio(0);

            BARF();
            STAGE_A(nb2, 1, kofs);
            __builtin_amdgcn_s_setprio(1);
            #pragma unroll
            for (int m = 0; m < 4; m++)
                #pragma unroll
                for (int n = 0; n < 2; n++)
                    #pragma unroll
                    for (int ks = 0; ks < 2; ks++)
                        acc[4 + m][n] = __builtin_amdgcn_mfma_f32_16x16x32_bf16(
                            af[m][ks], bf0[n][ks], acc[4 + m][n], 0, 0, 0);
            __builtin_amdgcn_s_setprio(0);
        }

        // epilogue: direct rows (head) or idx-scattered rows (tails)
        #pragma unroll
        for (int m = 0; m < 8; m++) {
            const int growb = mBase + (m >> 2) * 128 + wm * 64 + (m & 3) * 16 + lq * 4;
            #pragma unroll
            for (int i = 0; i < 4; i++) {
                int grow = growb + i;
                if (grow < Mlimit) {
                    int gr = idx ? idx[grow] : grow;
                    #pragma unroll
                    for (int n = 0; n < 4; n++) {
                        int gcol = nBase + (n >> 1) * 128 + wn * 32 + (n & 1) * 16 + lr;
                        if (gcol < Nn)
                            Cp[(size_t)gr * Nn + gcol] = acc[m][n][i];
                    }
                }
            }
        }
    }

    // ---- fill phase: non-head blocks only (head blocks are the long poles) ----
    if (!isHead) {
        for (int j = s; j < 8192; j += NB_NONHEAD) {
            int row   = j >> 1;
            int which = j & 1;
            int tg = target[row];
            bool in = which ? (tg >= C1 && tg < C2) : (tg >= C0 && tg < C1);
            if (!in) {
                float4* dst = (float4*)((which ? tail1 : tail0) + (size_t)row * 20000);
                float4 z = {0.f, 0.f, 0.f, 0.f};
                for (int q = t; q < 5000; q += 512) dst[q] = z;
            }
        }
    }
}

extern "C" void kernel_launch(void* const* d_in, const int* in_sizes, int n_in,
                              void* d_out, int out_size, void* d_ws, size_t ws_size,
                              hipStream_t stream)
{
    const float* input   = (const float*)d_in[0];
    const int*   target  = (const int*)  d_in[1];
    const float* head_w  = (const float*)d_in[2];
    const float* proj0_w = (const float*)d_in[3];
    const float* out0_w  = (const float*)d_in[4];
    const float* proj1_w = (const float*)d_in[5];
    const float* out1_w  = (const float*)d_in[6];

    const int N = 4096;

    float* out      = (float*)d_out;
    float* head_out = out;
    float* tail0    = head_out + (size_t)N * 10002;
    float* tail1    = tail0 + (size_t)N * 20000;
    float* o3       = tail1 + (size_t)N * 20000;
    float* o4       = o3 + N;
    float* o5       = o4 + N;

    unsigned short* ws = (unsigned short*)d_ws;
    unsigned short* in_bf  = ws + OFF_IN;
    unsigned short* hw_bf  = ws + OFF_HW;
    unsigned short* pjw_bf = ws + OFF_PJ;
    unsigned short* o0w_bf = ws + OFF_O0;
    unsigned short* o1w_bf = ws + OFF_O1;
    unsigned short* pp0c   = ws + OFF_PP0C;
    unsigned short* pp1c   = ws + OFF_PP1C;
    int* idx0 = (int*)(ws + OFF_IDX);
    int* idx1 = idx0 + 4096;
    int* cnts = idx1 + 4096;

    // 1. convert all operands to bf16 + routing outputs + (block 0) idx compaction
    convert_kernel<<<dim3((CVT_TOTAL / 8 + 255) / 256), dim3(256), 0, stream>>>(
        input, head_w, proj0_w, out0_w, proj1_w, out1_w, ws, target, o3, o4, o5,
        idx0, idx1, cnts);

    // 2. compacted projections, both bands (gathered A rows)
    proj_gather<<<dim3(2, N / BM, 2), dim3(256), 0, stream>>>(
        in_bf, pjw_bf, pp0c, pp1c, idx0, idx1, cnts);

    // 3. FUSED: head GEMM + tail GEMMs + non-band zero-fill (R11 core + tweaks)
    fused_kernel<<<dim3(NB_FUSED), dim3(512), 0, stream>>>(
        in_bf, hw_bf, pp0c, pp1c, o0w_bf, o1w_bf,
        head_out, tail0, tail1, idx0, idx1, cnts, target);
}